// Round 7
// baseline (81.187 us; speedup 1.0000x reference)
//
#include <hip/hip_runtime.h>
#include <hip/hip_bf16.h>
#include <math.h>

#define NDIM 4096
#define MDIM 4096
#define LDIM 512
#define KDIM 1024
#define NT   16     // K-tiles of BK=64

typedef short bf16x8 __attribute__((ext_vector_type(8)));
typedef float f32x4 __attribute__((ext_vector_type(4)));

#define GLOBAL_AS __attribute__((address_space(1)))
#define LDS_AS __attribute__((address_space(3)))

__device__ __align__(16) __hip_bfloat16 g_A[(size_t)NDIM * KDIM];
__device__ __align__(16) __hip_bfloat16 g_B[(size_t)MDIM * KDIM];

__device__ __forceinline__ void gload_lds16(void* lds, const void* g) {
  __builtin_amdgcn_global_load_lds((const GLOBAL_AS void*)g, (LDS_AS void*)lds, 16, 0, 0);
}

// ---------------------------------------------------------------------------
// scale_kernel: ws[0] = |var| / sum_l exp(-0.5*lam_l)
// ---------------------------------------------------------------------------
__global__ __launch_bounds__(512) void scale_kernel(const float* __restrict__ lam,
                                                    const float* __restrict__ var,
                                                    float* __restrict__ ws) {
  int l = threadIdx.x;
  float v = expf(-0.5f * lam[l]);
  #pragma unroll
  for (int off = 32; off > 0; off >>= 1) v += __shfl_down(v, off, 64);
  __shared__ float red[8];
  if ((l & 63) == 0) red[l >> 6] = v;
  __syncthreads();
  if (l == 0) {
    float t = 0.f;
    #pragma unroll
    for (int i = 0; i < 8; ++i) t += red[i];
    ws[0] = fabsf(var[0]) / t;
  }
}

// ---------------------------------------------------------------------------
// Phase kernel: 256 threads, 2 adjacent l's/thread -> 4B packed stores.
// ---------------------------------------------------------------------------
__global__ __launch_bounds__(256) void phase_kernel(const float* __restrict__ x,
                                                    const float* __restrict__ y,
                                                    const float* __restrict__ freqs,
                                                    const float* __restrict__ lam,
                                                    const float* __restrict__ ws) {
  int t = threadIdx.x;          // 0..255
  int l0 = 2 * t, l1 = 2 * t + 1;
  int r = blockIdx.x;           // 0..8191
  float s = ws[0];
  float w0 = expf(-0.5f * lam[l0]);
  float w1 = expf(-0.5f * lam[l1]);
  float a0 = freqs[l0 * 3 + 0], a1 = freqs[l0 * 3 + 1], a2 = freqs[l0 * 3 + 2];
  float b0 = freqs[l1 * 3 + 0], b1 = freqs[l1 * 3 + 1], b2 = freqs[l1 * 3 + 2];
  bool isA = (r < NDIM);
  int rr = isA ? r : (r - NDIM);
  const float* p = isA ? (x + (size_t)rr * 3) : (y + (size_t)rr * 3);
  float p0 = p[0], p1 = p[1], p2 = p[2];
  float px0 = p0 * a0 + p1 * a1 + p2 * a2;
  float px1 = p0 * b0 + p1 * b1 + p2 * b2;
  float sn0, cs0, sn1, cs1;
  __sincosf(px0, &sn0, &cs0);
  __sincosf(px1, &sn1, &cs1);
  float g0 = isA ? (w0 * s) : 1.0f;
  float g1 = isA ? (w1 * s) : 1.0f;
  __hip_bfloat16* dst = (isA ? g_A : g_B) + (size_t)rr * KDIM;
  __hip_bfloat162 cpair, spair;
  cpair.x = __float2bfloat16(g0 * cs0); cpair.y = __float2bfloat16(g1 * cs1);
  spair.x = __float2bfloat16(g0 * sn0); spair.y = __float2bfloat16(g1 * sn1);
  *(__hip_bfloat162*)&dst[l0]        = cpair;
  *(__hip_bfloat162*)&dst[LDIM + l0] = spair;
}

// ---------------------------------------------------------------------------
// GEMM: C[4096][4096] f32 = A @ B^T, bf16, K=1024.
// 128x128 tile, BK=64, 4 waves (2Mx2N, wave-tile 64x64), 64 KiB LDS
// -> 2 blocks/CU for cross-block overlap (m114). R4 schedule: fragments
// read ONE PHASE AHEAD, LGKM(8) partial wait, counted VMCNT(4) (never 0
// mid-loop), 1 barrier/phase, setprio around the 16-MFMA cluster.
// ---------------------------------------------------------------------------
__global__ __launch_bounds__(256, 2) void gemm_kernel(float* __restrict__ C) {
  __shared__ __align__(16) short Al[2][2][128 * 32];   // 32 KiB
  __shared__ __align__(16) short Bl[2][2][128 * 32];   // 32 KiB

  int bid = blockIdx.x;                    // 0..1023
  int swz = (bid & 7) * 128 + (bid >> 3);  // XCD swizzle (1024 % 8 == 0)
  int brow = (swz >> 5) * 128;
  int bcol = (swz & 31) * 128;

  int tid  = threadIdx.x;
  int lane = tid & 63;
  int wid  = tid >> 6;                     // 0..3
  int wm   = wid >> 1;                     // 0..1 -> rows wm*64..+63
  int wn   = wid & 1;                      // 0..1 -> cols wn*64..+63

  // ds_read offsets (swizzled: byte ^= ((row>>1)&3)<<4 within 64B rows)
  int fr   = lane & 15;
  int cs_  = ((lane >> 4) * 16) ^ (((fr >> 1) & 3) << 4);
  int offA[4], offB[4];
  #pragma unroll
  for (int m = 0; m < 4; ++m) offA[m] = (wm * 64 + m * 16 + fr) * 64 + cs_;
  #pragma unroll
  for (int n = 0; n < 4; ++n) offB[n] = (wn * 64 + n * 16 + fr) * 64 + cs_;

  // staging constants (pre-swizzled global source; LDS dest linear)
  int srow = tid >> 2;                                     // 0..63
  int scb  = ((tid & 3) * 16) ^ (((tid >> 3) & 3) << 4);   // byte in 64B row
  const short* gA = (const short*)g_A + (size_t)(brow + srow) * KDIM + scb / 2;
  const short* gB = (const short*)g_B + (size_t)(bcol + srow) * KDIM + scb / 2;

  f32x4 acc[4][4] = {};
  bf16x8 a0_0, a0_1, a0_2, a0_3, b0_0, b0_1, b0_2, b0_3;   // set 0 (kk even)
  bf16x8 a1_0, a1_1, a1_2, a1_3, b1_0, b1_1, b1_2, b1_3;   // set 1 (kk odd)

  // Stage one kk-half (128 rows x 32 cols) of A and B for tile T1: 4 issues.
#define STAGE(T1, KK)                                                        \
  {                                                                          \
    char* dA = (char*)(&Al[(T1) & 1][(KK)][0]) + tid * 16;                   \
    char* dB = (char*)(&Bl[(T1) & 1][(KK)][0]) + tid * 16;                   \
    const short* sA = gA + (T1) * 64 + (KK) * 32;                            \
    const short* sB = gB + (T1) * 64 + (KK) * 32;                            \
    gload_lds16(dA,        sA);                                              \
    gload_lds16(dA + 4096, sA + (size_t)64 * KDIM);                          \
    gload_lds16(dB,        sB);                                              \
    gload_lds16(dB + 4096, sB + (size_t)64 * KDIM);                          \
  }

#define VMCNT(N) asm volatile("s_waitcnt vmcnt(" #N ")" ::: "memory")
#define LGKM(N)  asm volatile("s_waitcnt lgkmcnt(" #N ")" ::: "memory")
#define SCHED0   __builtin_amdgcn_sched_barrier(0)
#define BAR      __builtin_amdgcn_s_barrier()

#define READ8(S, T, KK)                                                      \
  { const char* Ab_ = (const char*)(&Al[(T) & 1][(KK)][0]);                  \
    const char* Bb_ = (const char*)(&Bl[(T) & 1][(KK)][0]);                  \
    S##a0 = *(const bf16x8*)(Ab_ + offA[0]);                                 \
    S##a1 = *(const bf16x8*)(Ab_ + offA[1]);                                 \
    S##a2 = *(const bf16x8*)(Ab_ + offA[2]);                                 \
    S##a3 = *(const bf16x8*)(Ab_ + offA[3]);                                 \
    S##b0 = *(const bf16x8*)(Bb_ + offB[0]);                                 \
    S##b1 = *(const bf16x8*)(Bb_ + offB[1]);                                 \
    S##b2 = *(const bf16x8*)(Bb_ + offB[2]);                                 \
    S##b3 = *(const bf16x8*)(Bb_ + offB[3]); }

  // READ8(s0_, ...) fills a0_* / b0_* via token pasting: s0_##a0 -> a0_0 etc.
#define s0_a0 a0_0
#define s0_a1 a0_1
#define s0_a2 a0_2
#define s0_a3 a0_3
#define s0_b0 b0_0
#define s0_b1 b0_1
#define s0_b2 b0_2
#define s0_b3 b0_3
#define s1_a0 a1_0
#define s1_a1 a1_1
#define s1_a2 a1_2
#define s1_a3 a1_3
#define s1_b0 b1_0
#define s1_b1 b1_1
#define s1_b2 b1_2
#define s1_b3 b1_3

#define MFMA4(I, AF, B0, B1, B2, B3)                                                  \
  acc[I][0] = __builtin_amdgcn_mfma_f32_16x16x32_bf16(AF, B0, acc[I][0], 0, 0, 0);    \
  acc[I][1] = __builtin_amdgcn_mfma_f32_16x16x32_bf16(AF, B1, acc[I][1], 0, 0, 0);    \
  acc[I][2] = __builtin_amdgcn_mfma_f32_16x16x32_bf16(AF, B2, acc[I][2], 0, 0, 0);    \
  acc[I][3] = __builtin_amdgcn_mfma_f32_16x16x32_bf16(AF, B3, acc[I][3], 0, 0, 0);

#define MFMA16(S)                                                            \
  __builtin_amdgcn_s_setprio(1);                                             \
  MFMA4(0, S##a0, S##b0, S##b1, S##b2, S##b3)                                \
  MFMA4(1, S##a1, S##b0, S##b1, S##b2, S##b3)                                \
  MFMA4(2, S##a2, S##b0, S##b1, S##b2, S##b3)                                \
  MFMA4(3, S##a3, S##b0, S##b1, S##b2, S##b3)                                \
  __builtin_amdgcn_s_setprio(0);

  // ---- prologue: stage tile0 (k0,k1) + tile1 k0; wait tile0; read (0,0) ----
  STAGE(0, 0);
  STAGE(0, 1);
  STAGE(1, 0);
  VMCNT(4);                      // tile 0 landed; (1,k0) in flight (4)
  BAR;
  READ8(s0_, 0, 0);

  // ---- main loop t = 0..13 uniform; peel t = 14, 15 ----
  // Ledger invariant at top of iter t: vmem outstanding = {(t+1,k0):4}
  for (int t = 0; t < 14; ++t) {
    // phase (t,0): compute set0 = (t,k0); read-ahead (t,k1); stage (t+1,k1)
    READ8(s1_, t, 1);
    LGKM(8); SCHED0;             // set0 ready; set1's 8 reads stay in flight
    MFMA16(s0_);
    STAGE(t + 1, 1);             // outstanding: {(t+1,k0):4, (t+1,k1):4}
    VMCNT(4);                    // retire (t+1,k0) -> ph1 may read it
    BAR;
    // phase (t,1): compute set1 = (t,k1); read-ahead (t+1,k0); stage (t+2,k0)
    READ8(s0_, t + 1, 0);
    LGKM(8); SCHED0;
    MFMA16(s1_);
    STAGE(t + 2, 0);             // outstanding: {(t+1,k1):4, (t+2,k0):4}
    VMCNT(4);                    // retire (t+1,k1) -> next ph0 may read it
    BAR;
  }
  // t = 14
  READ8(s1_, 14, 1);
  LGKM(8); SCHED0;
  MFMA16(s0_);
  STAGE(15, 1);                  // outstanding: {(15,k0):4, (15,k1):4}
  VMCNT(4);                      // retire (15,k0)
  BAR;
  READ8(s0_, 15, 0);
  LGKM(8); SCHED0;
  MFMA16(s1_);
  VMCNT(0);                      // retire (15,k1)
  BAR;
  // t = 15 (no staging, no barriers needed)
  READ8(s1_, 15, 1);
  LGKM(8); SCHED0;
  MFMA16(s0_);
  LGKM(0); SCHED0;
  MFMA16(s1_);

  // ---- epilogue: C/D layout col=lane&15, row=(lane>>4)*4+j ----
  int crow = brow + wm * 64 + (lane >> 4) * 4;
  int ccol = bcol + wn * 64 + (lane & 15);
  #pragma unroll
  for (int mi = 0; mi < 4; ++mi)
    #pragma unroll
    for (int n = 0; n < 4; ++n)
      #pragma unroll
      for (int j = 0; j < 4; ++j)
        C[(size_t)(crow + mi * 16 + j) * MDIM + (ccol + n * 16)] = acc[mi][n][j];
}

extern "C" void kernel_launch(void* const* d_in, const int* in_sizes, int n_in,
                              void* d_out, int out_size, void* d_ws, size_t ws_size,
                              hipStream_t stream) {
  const float* x     = (const float*)d_in[0];
  const float* y     = (const float*)d_in[1];
  const float* freqs = (const float*)d_in[2];
  const float* lam   = (const float*)d_in[3];
  const float* var   = (const float*)d_in[4];
  float* out = (float*)d_out;
  float* ws  = (float*)d_ws;

  hipLaunchKernelGGL(scale_kernel, dim3(1), dim3(512), 0, stream, lam, var, ws);
  hipLaunchKernelGGL(phase_kernel, dim3(NDIM + MDIM), dim3(256), 0, stream,
                     x, y, freqs, lam, ws);
  hipLaunchKernelGGL(gemm_kernel, dim3((NDIM / 128) * (MDIM / 128)), dim3(256), 0, stream,
                     out);
}

// Round 9
// 65.027 us; speedup vs baseline: 1.2485x; 1.2485x over previous
//
#include <hip/hip_runtime.h>
#include <hip/hip_bf16.h>
#include <math.h>

#define NDIM 4096
#define MDIM 4096
#define LDIM 512
#define KDIM 1024

typedef short bf16x8 __attribute__((ext_vector_type(8)));
typedef float f32x4 __attribute__((ext_vector_type(4)));

#define GLOBAL_AS __attribute__((address_space(1)))
#define LDS_AS __attribute__((address_space(3)))

__device__ __align__(16) __hip_bfloat16 g_A[(size_t)NDIM * KDIM];
__device__ __align__(16) __hip_bfloat16 g_B[(size_t)MDIM * KDIM];

__device__ __forceinline__ void gload_lds16(void* lds, const void* g) {
  __builtin_amdgcn_global_load_lds((const GLOBAL_AS void*)g, (LDS_AS void*)lds, 16, 0, 0);
}

// ---------------------------------------------------------------------------
// scale_kernel: ws[0] = |var| / sum_l exp(-0.5*lam_l)
// ---------------------------------------------------------------------------
__global__ __launch_bounds__(512) void scale_kernel(const float* __restrict__ lam,
                                                    const float* __restrict__ var,
                                                    float* __restrict__ ws) {
  int l = threadIdx.x;
  float v = expf(-0.5f * lam[l]);
  #pragma unroll
  for (int off = 32; off > 0; off >>= 1) v += __shfl_down(v, off, 64);
  __shared__ float red[8];
  if ((l & 63) == 0) red[l >> 6] = v;
  __syncthreads();
  if (l == 0) {
    float t = 0.f;
    #pragma unroll
    for (int i = 0; i < 8; ++i) t += red[i];
    ws[0] = fabsf(var[0]) / t;
  }
}

// ---------------------------------------------------------------------------
// Phase kernel: 256 threads, 2 adjacent l's/thread -> 4B packed stores.
// ---------------------------------------------------------------------------
__global__ __launch_bounds__(256) void phase_kernel(const float* __restrict__ x,
                                                    const float* __restrict__ y,
                                                    const float* __restrict__ freqs,
                                                    const float* __restrict__ lam,
                                                    const float* __restrict__ ws) {
  int t = threadIdx.x;          // 0..255
  int l0 = 2 * t, l1 = 2 * t + 1;
  int r = blockIdx.x;           // 0..8191
  float s = ws[0];
  float w0 = expf(-0.5f * lam[l0]);
  float w1 = expf(-0.5f * lam[l1]);
  float a0 = freqs[l0 * 3 + 0], a1 = freqs[l0 * 3 + 1], a2 = freqs[l0 * 3 + 2];
  float b0 = freqs[l1 * 3 + 0], b1 = freqs[l1 * 3 + 1], b2 = freqs[l1 * 3 + 2];
  bool isA = (r < NDIM);
  int rr = isA ? r : (r - NDIM);
  const float* p = isA ? (x + (size_t)rr * 3) : (y + (size_t)rr * 3);
  float p0 = p[0], p1 = p[1], p2 = p[2];
  float px0 = p0 * a0 + p1 * a1 + p2 * a2;
  float px1 = p0 * b0 + p1 * b1 + p2 * b2;
  float sn0, cs0, sn1, cs1;
  __sincosf(px0, &sn0, &cs0);
  __sincosf(px1, &sn1, &cs1);
  float g0 = isA ? (w0 * s) : 1.0f;
  float g1 = isA ? (w1 * s) : 1.0f;
  __hip_bfloat16* dst = (isA ? g_A : g_B) + (size_t)rr * KDIM;
  __hip_bfloat162 cpair, spair;
  cpair.x = __float2bfloat16(g0 * cs0); cpair.y = __float2bfloat16(g1 * cs1);
  spair.x = __float2bfloat16(g0 * sn0); spair.y = __float2bfloat16(g1 * sn1);
  *(__hip_bfloat162*)&dst[l0]        = cpair;
  *(__hip_bfloat162*)&dst[LDIM + l0] = spair;
}

// ---------------------------------------------------------------------------
// GEMM: C[4096][4096] f32 = A @ B^T, bf16, K=1024. m201-style 8-phase,
// 256x256 tile, BK=64, 8 waves (2Mx4N, wave-tile 128x64). LDS 128 KiB.
// RACE FIX vs R7: STAGE_A(T+3,0) moved p6 -> p8 (Al[1][0] rows 64..127 are
// still read by p7's AREAD(1,1); staging it at p6 overwrote live data).
// Per-wave FIFO ledger: iter-entry outstanding = {B(T+1,0),B(T+1,1),A(T+1,0)};
// p4 VMCNT(6) retires tile T+1, p8 VMCNT(6) retires tile T+2. vmcnt never 0
// mid-loop; peel uses VMCNT(0) once at p4.
// ---------------------------------------------------------------------------
__global__ __launch_bounds__(512, 2) void gemm_kernel(float* __restrict__ C) {
  __shared__ __align__(16) short Al[2][2][128 * 64];   // 64 KiB
  __shared__ __align__(16) short Bl[2][2][128 * 64];   // 64 KiB

  int bid = blockIdx.x;                   // 0..255
  int swz = (bid & 7) * 32 + (bid >> 3);  // XCD swizzle (256 % 8 == 0)
  int brow = (swz >> 4) * 256;
  int bcol = (swz & 15) * 256;

  int tid  = threadIdx.x;
  int lane = tid & 63;
  int wid  = tid >> 6;                    // 0..7
  int wm   = wid >> 2;                    // 0..1: rows wm*128..+127 (slab A[wm])
  int wn   = wid & 3;                     // 0..3: cols wn*64..+63 (slab B[wn>>1])

  // ds_read offsets. Row pitch 128 B; swizzle byte ^= ((row&7)<<4).
  int fr    = lane & 15;
  int u     = (lane >> 4) * 16;           // 16B sub-col within K-half
  int xs    = (fr & 7) << 4;
  int swzk0 = u ^ xs;                     // kk=0 col bytes, swizzled
  int swzk1 = (64 + u) ^ xs;              // kk=1
  int aRow  = fr * 128;
  int bRow  = ((wn & 1) * 64 + fr) * 128;

  // staging: thread t -> local row tid>>3 (0..63), 16B slot tid&7
  int srow    = tid >> 3;
  int scol8   = tid & 7;
  int dst_off = srow * 128 + scol8 * 16;                 // linear LDS dest
  int swzsrc  = (scol8 * 8) ^ ((srow & 7) << 3);         // shorts, inverse-swz
  const short* gAs = (const short*)g_A + (size_t)(brow + srow) * KDIM + swzsrc;
  const short* gBs = (const short*)g_B + (size_t)(bcol + srow) * KDIM + swzsrc;

  f32x4 acc[8][4] = {};
  bf16x8 a00, a01, a10, a11, a20, a21, a30, a31;   // A-half frags (4m x 2kk)
  bf16x8 b00, b01, b10, b11;                       // B set b (nh0: 2n x 2kk)
  bf16x8 c00, c01, c10, c11;                       // B set c (nh1)

#define STAGE_A(T1, MH) {                                                    \
    char* d_ = (char*)&Al[(T1) & 1][MH][0] + dst_off;                        \
    const short* s_ = gAs + ((size_t)(MH) * 128) * KDIM + (T1) * 64;         \
    gload_lds16(d_, s_);                                                     \
    gload_lds16(d_ + 8192, s_ + (size_t)64 * KDIM); }

#define STAGE_B(T1, NH) {                                                    \
    char* d_ = (char*)&Bl[(T1) & 1][NH][0] + dst_off;                        \
    const short* s_ = gBs + ((size_t)(NH) * 128) * KDIM + (T1) * 64;         \
    gload_lds16(d_, s_);                                                     \
    gload_lds16(d_ + 8192, s_ + (size_t)64 * KDIM); }

#define VMCNT(N) asm volatile("s_waitcnt vmcnt(" #N ")" ::: "memory")
#define LGKM(N)  asm volatile("s_waitcnt lgkmcnt(" #N ")" ::: "memory")
#define SCHED0   __builtin_amdgcn_sched_barrier(0)
#define BAR      __builtin_amdgcn_s_barrier()

#define AREAD(BUF, MH) {                                                     \
    const char* P = (const char*)&Al[BUF][wm][0] + aRow + (MH) * 8192;       \
    a00 = *(const bf16x8*)(P + 0    + swzk0);                                \
    a01 = *(const bf16x8*)(P + 0    + swzk1);                                \
    a10 = *(const bf16x8*)(P + 2048 + swzk0);                                \
    a11 = *(const bf16x8*)(P + 2048 + swzk1);                                \
    a20 = *(const bf16x8*)(P + 4096 + swzk0);                                \
    a21 = *(const bf16x8*)(P + 4096 + swzk1);                                \
    a30 = *(const bf16x8*)(P + 6144 + swzk0);                                \
    a31 = *(const bf16x8*)(P + 6144 + swzk1); }

#define BREAD(BUF, NH, S) {                                                  \
    const char* P = (const char*)&Bl[BUF][wn >> 1][0] + bRow + (NH) * 4096;  \
    S##00 = *(const bf16x8*)(P + 0    + swzk0);                              \
    S##01 = *(const bf16x8*)(P + 0    + swzk1);                              \
    S##10 = *(const bf16x8*)(P + 2048 + swzk0);                              \
    S##11 = *(const bf16x8*)(P + 2048 + swzk1); }

#define MF(M, N, AF, BF)                                                     \
  acc[M][N] = __builtin_amdgcn_mfma_f32_16x16x32_bf16(AF, BF, acc[M][N], 0, 0, 0);

#define QMFMA(MH, NH, S)                                                     \
  __builtin_amdgcn_s_setprio(1);                                             \
  MF((MH)*4+0, (NH)*2+0, a00, S##00) MF((MH)*4+0, (NH)*2+1, a00, S##10)      \
  MF((MH)*4+1, (NH)*2+0, a10, S##00) MF((MH)*4+1, (NH)*2+1, a10, S##10)      \
  MF((MH)*4+2, (NH)*2+0, a20, S##00) MF((MH)*4+2, (NH)*2+1, a20, S##10)      \
  MF((MH)*4+3, (NH)*2+0, a30, S##00) MF((MH)*4+3, (NH)*2+1, a30, S##10)      \
  MF((MH)*4+0, (NH)*2+0, a01, S##01) MF((MH)*4+0, (NH)*2+1, a01, S##11)      \
  MF((MH)*4+1, (NH)*2+0, a11, S##01) MF((MH)*4+1, (NH)*2+1, a11, S##11)      \
  MF((MH)*4+2, (NH)*2+0, a21, S##01) MF((MH)*4+2, (NH)*2+1, a21, S##11)      \
  MF((MH)*4+3, (NH)*2+0, a31, S##01) MF((MH)*4+3, (NH)*2+1, a31, S##11)      \
  __builtin_amdgcn_s_setprio(0);

  // ---- prologue: tile 0 fully + tile 1 {A0,B0,B1}; 3 half-tiles in flight --
  STAGE_A(0, 0); STAGE_A(0, 1); STAGE_B(0, 0); STAGE_B(0, 1);
  STAGE_A(1, 0); STAGE_B(1, 0); STAGE_B(1, 1);
  VMCNT(6);                      // tile 0 landed; tile-1 halves (6) in flight
  BAR;

  // ---- main loop i=0..6 (tiles T=2i, T+1); iter 7 peeled ----
  for (int i = 0; i < 7; ++i) {
    int T = 2 * i;
    // p1: Q(mh0,nh0) of tile T; reads A0-half(8) + Bnh0(4); stage A1(T+1)
    AREAD(0, 0); BREAD(0, 0, b); STAGE_A(T + 1, 1); LGKM(8);
    BAR; LGKM(0); SCHED0;
    QMFMA(0, 0, b);
    BAR;
    // p2: Q(mh0,nh1); reads Bnh1(4)
    BREAD(0, 1, c);
    BAR; LGKM(0); SCHED0;
    QMFMA(0, 1, c);
    BAR;
    // p3: Q(mh1,nh1); reads A1-half(8); stage B0(T+2)
    AREAD(0, 1); STAGE_B(T + 2, 0);
    BAR; LGKM(0); SCHED0;
    QMFMA(1, 1, c);
    BAR;
    // p4: Q(mh1,nh0); 0 reads; stage A0(T+2)+A1(T+2); vmcnt(6) -> tile T+1 in
    STAGE_A(T + 2, 0); STAGE_A(T + 2, 1);
    BAR; SCHED0;
    QMFMA(1, 0, b);
    VMCNT(6);
    BAR;
    // p5: tile T+1 (buf1) Q(mh0,nh0); stage B1(T+2)
    AREAD(1, 0); BREAD(1, 0, b); STAGE_B(T + 2, 1); LGKM(8);
    BAR; LGKM(0); SCHED0;
    QMFMA(0, 0, b);
    BAR;
    // p6: Q(mh0,nh1); NO stage (A0(T+3) here raced p7's AREAD(1,1) in R7)
    BREAD(1, 1, c);
    BAR; LGKM(0); SCHED0;
    QMFMA(0, 1, c);
    BAR;
    // p7: Q(mh1,nh1); reads A1-half(8); stage B0(T+3)
    AREAD(1, 1); STAGE_B(T + 3, 0);
    BAR; LGKM(0); SCHED0;
    QMFMA(1, 1, c);
    BAR;
    // p8: Q(mh1,nh0); stage B1(T+3) + A0(T+3) (safe: after p7's reads);
    //     vmcnt(6) -> tile T+2 landed
    STAGE_B(T + 3, 1); STAGE_A(T + 3, 0);
    BAR; SCHED0;
    QMFMA(1, 0, b);
    VMCNT(6);
    BAR;
  }

  // ---- peeled iter 7: tiles 14 (buf0), 15 (buf1); only stage = A1(15) ----
  AREAD(0, 0); BREAD(0, 0, b); STAGE_A(15, 1); LGKM(8);
  BAR; LGKM(0); SCHED0; QMFMA(0, 0, b); BAR;
  BREAD(0, 1, c);
  BAR; LGKM(0); SCHED0; QMFMA(0, 1, c); BAR;
  AREAD(0, 1);
  BAR; LGKM(0); SCHED0; QMFMA(1, 1, c); BAR;
  BAR; SCHED0; QMFMA(1, 0, b);
  VMCNT(0);                      // retire all of tile 15 before p5..p7 read it
  BAR;
  AREAD(1, 0); BREAD(1, 0, b); LGKM(8);
  BAR; LGKM(0); SCHED0; QMFMA(0, 0, b); BAR;
  BREAD(1, 1, c);
  BAR; LGKM(0); SCHED0; QMFMA(0, 1, c); BAR;
  AREAD(1, 1);
  BAR; LGKM(0); SCHED0; QMFMA(1, 1, c); BAR;
  QMFMA(1, 0, b);                // final quadrant

  // ---- epilogue: C/D layout col=lane&15, row=(lane>>4)*4+j ----
  int crow = brow + wm * 128 + (lane >> 4) * 4;
  int ccol = bcol + wn * 64 + (lane & 15);
  #pragma unroll
  for (int mi = 0; mi < 8; ++mi)
    #pragma unroll
    for (int n = 0; n < 4; ++n)
      #pragma unroll
      for (int j = 0; j < 4; ++j)
        C[(size_t)(crow + mi * 16 + j) * MDIM + (ccol + n * 16)] = acc[mi][n][j];
}

extern "C" void kernel_launch(void* const* d_in, const int* in_sizes, int n_in,
                              void* d_out, int out_size, void* d_ws, size_t ws_size,
                              hipStream_t stream) {
  const float* x     = (const float*)d_in[0];
  const float* y     = (const float*)d_in[1];
  const float* freqs = (const float*)d_in[2];
  const float* lam   = (const float*)d_in[3];
  const float* var   = (const float*)d_in[4];
  float* out = (float*)d_out;
  float* ws  = (float*)d_ws;

  hipLaunchKernelGGL(scale_kernel, dim3(1), dim3(512), 0, stream, lam, var, ws);
  hipLaunchKernelGGL(phase_kernel, dim3(NDIM + MDIM), dim3(256), 0, stream,
                     x, y, freqs, lam, ws);
  hipLaunchKernelGGL(gemm_kernel, dim3((NDIM / 256) * (MDIM / 256)), dim3(512), 0, stream,
                     out);
}

// Round 10
// 64.313 us; speedup vs baseline: 1.2624x; 1.0111x over previous
//
#include <hip/hip_runtime.h>
#include <hip/hip_bf16.h>
#include <math.h>

#define NDIM 4096
#define MDIM 4096
#define LDIM 512
#define KDIM 1024
#define PH_ROWS 8

typedef short bf16x8 __attribute__((ext_vector_type(8)));
typedef float f32x4 __attribute__((ext_vector_type(4)));

#define GLOBAL_AS __attribute__((address_space(1)))
#define LDS_AS __attribute__((address_space(3)))

__device__ __align__(16) __hip_bfloat16 g_A[(size_t)NDIM * KDIM];
__device__ __align__(16) __hip_bfloat16 g_B[(size_t)MDIM * KDIM];

__device__ __forceinline__ void gload_lds16(void* lds, const void* g) {
  __builtin_amdgcn_global_load_lds((const GLOBAL_AS void*)g, (LDS_AS void*)lds, 16, 0, 0);
}

// ---------------------------------------------------------------------------
// scale_kernel: ws[0] = |var| / sum_l exp(-0.5*lam_l)
// ---------------------------------------------------------------------------
__global__ __launch_bounds__(512) void scale_kernel(const float* __restrict__ lam,
                                                    const float* __restrict__ var,
                                                    float* __restrict__ ws) {
  int l = threadIdx.x;
  float v = expf(-0.5f * lam[l]);
  #pragma unroll
  for (int off = 32; off > 0; off >>= 1) v += __shfl_down(v, off, 64);
  __shared__ float red[8];
  if ((l & 63) == 0) red[l >> 6] = v;
  __syncthreads();
  if (l == 0) {
    float t = 0.f;
    #pragma unroll
    for (int i = 0; i < 8; ++i) t += red[i];
    ws[0] = fabsf(var[0]) / t;
  }
}

// ---------------------------------------------------------------------------
// Phase kernel: 256 threads, 2 adjacent l's/thread, 8 ROWS per block so the
// freqs/lam reads (8 KB/block) amortize over 8 rows (64 MB -> 8 MB of L2
// traffic). Blocks 0..511 -> A rows, 512..1023 -> B rows.
// ---------------------------------------------------------------------------
__global__ __launch_bounds__(256) void phase_kernel(const float* __restrict__ x,
                                                    const float* __restrict__ y,
                                                    const float* __restrict__ freqs,
                                                    const float* __restrict__ lam,
                                                    const float* __restrict__ ws) {
  int t = threadIdx.x;          // 0..255
  int l0 = 2 * t, l1 = 2 * t + 1;
  int blk = blockIdx.x;         // 0..1023
  float s = ws[0];
  float w0 = expf(-0.5f * lam[l0]);
  float w1 = expf(-0.5f * lam[l1]);
  float a0 = freqs[l0 * 3 + 0], a1 = freqs[l0 * 3 + 1], a2 = freqs[l0 * 3 + 2];
  float b0 = freqs[l1 * 3 + 0], b1 = freqs[l1 * 3 + 1], b2 = freqs[l1 * 3 + 2];
  bool isA = (blk < 512);
  int r0 = (isA ? blk : blk - 512) * PH_ROWS;
  const float* P = isA ? x : y;
  __hip_bfloat16* base = isA ? g_A : g_B;
  float g0 = isA ? (w0 * s) : 1.0f;
  float g1 = isA ? (w1 * s) : 1.0f;
  #pragma unroll
  for (int j = 0; j < PH_ROWS; ++j) {
    int rr = r0 + j;
    float p0 = P[rr * 3 + 0], p1 = P[rr * 3 + 1], p2 = P[rr * 3 + 2];
    float px0 = p0 * a0 + p1 * a1 + p2 * a2;
    float px1 = p0 * b0 + p1 * b1 + p2 * b2;
    float sn0, cs0, sn1, cs1;
    __sincosf(px0, &sn0, &cs0);
    __sincosf(px1, &sn1, &cs1);
    __hip_bfloat16* dst = base + (size_t)rr * KDIM;
    __hip_bfloat162 cpair, spair;
    cpair.x = __float2bfloat16(g0 * cs0); cpair.y = __float2bfloat16(g1 * cs1);
    spair.x = __float2bfloat16(g0 * sn0); spair.y = __float2bfloat16(g1 * sn1);
    *(__hip_bfloat162*)&dst[l0]        = cpair;
    *(__hip_bfloat162*)&dst[LDIM + l0] = spair;
  }
}

// ---------------------------------------------------------------------------
// GEMM: C[4096][4096] f32 = A @ B^T, bf16, K=1024. R9's verified 8-phase
// schedule, UNCHANGED except blockIdx->tile mapping: locality supertile
// swizzle. XCD x (= bid&7, dispatch round-robin) processes supertiles
// {2x, 2x+1}; each supertile = 4x4 region of 256^2 tiles (1024x1024 out),
// the pair shares one A row-band -> per-XCD working set ~6 MB (vs 10),
// L3 refetch ~4x lower. Bijective: b<->(x,slot)<->(sup,w)<->(trow,tcol).
// ---------------------------------------------------------------------------
__global__ __launch_bounds__(512, 2) void gemm_kernel(float* __restrict__ C) {
  __shared__ __align__(16) short Al[2][2][128 * 64];   // 64 KiB
  __shared__ __align__(16) short Bl[2][2][128 * 64];   // 64 KiB

  int bid = blockIdx.x;                   // 0..255
  int xcd = bid & 7;
  int slt = bid >> 3;                     // 0..31 within XCD
  int sup = 2 * xcd + (slt >> 4);         // 0..15 supertile (4x4 grid)
  int w_  = slt & 15;
  int trow = (sup >> 2) * 4 + (w_ >> 2);
  int tcol = (sup & 3) * 4 + (w_ & 3);
  int brow = trow * 256;
  int bcol = tcol * 256;

  int tid  = threadIdx.x;
  int lane = tid & 63;
  int wid  = tid >> 6;                    // 0..7
  int wm   = wid >> 2;                    // 0..1: rows wm*128..+127 (slab A[wm])
  int wn   = wid & 3;                     // 0..3: cols wn*64..+63 (slab B[wn>>1])

  // ds_read offsets. Row pitch 128 B; swizzle byte ^= ((row&7)<<4).
  int fr    = lane & 15;
  int u     = (lane >> 4) * 16;           // 16B sub-col within K-half
  int xs    = (fr & 7) << 4;
  int swzk0 = u ^ xs;                     // kk=0 col bytes, swizzled
  int swzk1 = (64 + u) ^ xs;              // kk=1
  int aRow  = fr * 128;
  int bRow  = ((wn & 1) * 64 + fr) * 128;

  // staging: thread t -> local row tid>>3 (0..63), 16B slot tid&7
  int srow    = tid >> 3;
  int scol8   = tid & 7;
  int dst_off = srow * 128 + scol8 * 16;                 // linear LDS dest
  int swzsrc  = (scol8 * 8) ^ ((srow & 7) << 3);         // shorts, inverse-swz
  const short* gAs = (const short*)g_A + (size_t)(brow + srow) * KDIM + swzsrc;
  const short* gBs = (const short*)g_B + (size_t)(bcol + srow) * KDIM + swzsrc;

  f32x4 acc[8][4] = {};
  bf16x8 a00, a01, a10, a11, a20, a21, a30, a31;   // A-half frags (4m x 2kk)
  bf16x8 b00, b01, b10, b11;                       // B set b (nh0: 2n x 2kk)
  bf16x8 c00, c01, c10, c11;                       // B set c (nh1)

#define STAGE_A(T1, MH) {                                                    \
    char* d_ = (char*)&Al[(T1) & 1][MH][0] + dst_off;                        \
    const short* s_ = gAs + ((size_t)(MH) * 128) * KDIM + (T1) * 64;         \
    gload_lds16(d_, s_);                                                     \
    gload_lds16(d_ + 8192, s_ + (size_t)64 * KDIM); }

#define STAGE_B(T1, NH) {                                                    \
    char* d_ = (char*)&Bl[(T1) & 1][NH][0] + dst_off;                        \
    const short* s_ = gBs + ((size_t)(NH) * 128) * KDIM + (T1) * 64;         \
    gload_lds16(d_, s_);                                                     \
    gload_lds16(d_ + 8192, s_ + (size_t)64 * KDIM); }

#define VMCNT(N) asm volatile("s_waitcnt vmcnt(" #N ")" ::: "memory")
#define LGKM(N)  asm volatile("s_waitcnt lgkmcnt(" #N ")" ::: "memory")
#define SCHED0   __builtin_amdgcn_sched_barrier(0)
#define BAR      __builtin_amdgcn_s_barrier()

#define AREAD(BUF, MH) {                                                     \
    const char* P = (const char*)&Al[BUF][wm][0] + aRow + (MH) * 8192;       \
    a00 = *(const bf16x8*)(P + 0    + swzk0);                                \
    a01 = *(const bf16x8*)(P + 0    + swzk1);                                \
    a10 = *(const bf16x8*)(P + 2048 + swzk0);                                \
    a11 = *(const bf16x8*)(P + 2048 + swzk1);                                \
    a20 = *(const bf16x8*)(P + 4096 + swzk0);                                \
    a21 = *(const bf16x8*)(P + 4096 + swzk1);                                \
    a30 = *(const bf16x8*)(P + 6144 + swzk0);                                \
    a31 = *(const bf16x8*)(P + 6144 + swzk1); }

#define BREAD(BUF, NH, S) {                                                  \
    const char* P = (const char*)&Bl[BUF][wn >> 1][0] + bRow + (NH) * 4096;  \
    S##00 = *(const bf16x8*)(P + 0    + swzk0);                              \
    S##01 = *(const bf16x8*)(P + 0    + swzk1);                              \
    S##10 = *(const bf16x8*)(P + 2048 + swzk0);                              \
    S##11 = *(const bf16x8*)(P + 2048 + swzk1); }

#define MF(M, N, AF, BF)                                                     \
  acc[M][N] = __builtin_amdgcn_mfma_f32_16x16x32_bf16(AF, BF, acc[M][N], 0, 0, 0);

#define QMFMA(MH, NH, S)                                                     \
  __builtin_amdgcn_s_setprio(1);                                             \
  MF((MH)*4+0, (NH)*2+0, a00, S##00) MF((MH)*4+0, (NH)*2+1, a00, S##10)      \
  MF((MH)*4+1, (NH)*2+0, a10, S##00) MF((MH)*4+1, (NH)*2+1, a10, S##10)      \
  MF((MH)*4+2, (NH)*2+0, a20, S##00) MF((MH)*4+2, (NH)*2+1, a20, S##10)      \
  MF((MH)*4+3, (NH)*2+0, a30, S##00) MF((MH)*4+3, (NH)*2+1, a30, S##10)      \
  MF((MH)*4+0, (NH)*2+0, a01, S##01) MF((MH)*4+0, (NH)*2+1, a01, S##11)      \
  MF((MH)*4+1, (NH)*2+0, a11, S##01) MF((MH)*4+1, (NH)*2+1, a11, S##11)      \
  MF((MH)*4+2, (NH)*2+0, a21, S##01) MF((MH)*4+2, (NH)*2+1, a21, S##11)      \
  MF((MH)*4+3, (NH)*2+0, a31, S##01) MF((MH)*4+3, (NH)*2+1, a31, S##11)      \
  __builtin_amdgcn_s_setprio(0);

  // ---- prologue: tile 0 fully + tile 1 {A0,B0,B1}; 3 half-tiles in flight --
  STAGE_A(0, 0); STAGE_A(0, 1); STAGE_B(0, 0); STAGE_B(0, 1);
  STAGE_A(1, 0); STAGE_B(1, 0); STAGE_B(1, 1);
  VMCNT(6);                      // tile 0 landed; tile-1 halves (6) in flight
  BAR;

  // ---- main loop i=0..6 (tiles T=2i, T+1); iter 7 peeled ----
  for (int i = 0; i < 7; ++i) {
    int T = 2 * i;
    // p1: Q(mh0,nh0) of tile T; reads A0-half(8) + Bnh0(4); stage A1(T+1)
    AREAD(0, 0); BREAD(0, 0, b); STAGE_A(T + 1, 1); LGKM(8);
    BAR; LGKM(0); SCHED0;
    QMFMA(0, 0, b);
    BAR;
    // p2: Q(mh0,nh1); reads Bnh1(4)
    BREAD(0, 1, c);
    BAR; LGKM(0); SCHED0;
    QMFMA(0, 1, c);
    BAR;
    // p3: Q(mh1,nh1); reads A1-half(8); stage B0(T+2)
    AREAD(0, 1); STAGE_B(T + 2, 0);
    BAR; LGKM(0); SCHED0;
    QMFMA(1, 1, c);
    BAR;
    // p4: Q(mh1,nh0); 0 reads; stage A0(T+2)+A1(T+2); vmcnt(6) -> tile T+1 in
    STAGE_A(T + 2, 0); STAGE_A(T + 2, 1);
    BAR; SCHED0;
    QMFMA(1, 0, b);
    VMCNT(6);
    BAR;
    // p5: tile T+1 (buf1) Q(mh0,nh0); stage B1(T+2)
    AREAD(1, 0); BREAD(1, 0, b); STAGE_B(T + 2, 1); LGKM(8);
    BAR; LGKM(0); SCHED0;
    QMFMA(0, 0, b);
    BAR;
    // p6: Q(mh0,nh1); NO stage (A0(T+3) here raced p7's AREAD(1,1) in R7)
    BREAD(1, 1, c);
    BAR; LGKM(0); SCHED0;
    QMFMA(0, 1, c);
    BAR;
    // p7: Q(mh1,nh1); reads A1-half(8); stage B0(T+3)
    AREAD(1, 1); STAGE_B(T + 3, 0);
    BAR; LGKM(0); SCHED0;
    QMFMA(1, 1, c);
    BAR;
    // p8: Q(mh1,nh0); stage B1(T+3) + A0(T+3) (safe: after p7's reads);
    //     vmcnt(6) -> tile T+2 landed
    STAGE_B(T + 3, 1); STAGE_A(T + 3, 0);
    BAR; SCHED0;
    QMFMA(1, 0, b);
    VMCNT(6);
    BAR;
  }

  // ---- peeled iter 7: tiles 14 (buf0), 15 (buf1); only stage = A1(15) ----
  AREAD(0, 0); BREAD(0, 0, b); STAGE_A(15, 1); LGKM(8);
  BAR; LGKM(0); SCHED0; QMFMA(0, 0, b); BAR;
  BREAD(0, 1, c);
  BAR; LGKM(0); SCHED0; QMFMA(0, 1, c); BAR;
  AREAD(0, 1);
  BAR; LGKM(0); SCHED0; QMFMA(1, 1, c); BAR;
  BAR; SCHED0; QMFMA(1, 0, b);
  VMCNT(0);                      // retire all of tile 15 before p5..p7 read it
  BAR;
  AREAD(1, 0); BREAD(1, 0, b); LGKM(8);
  BAR; LGKM(0); SCHED0; QMFMA(0, 0, b); BAR;
  BREAD(1, 1, c);
  BAR; LGKM(0); SCHED0; QMFMA(0, 1, c); BAR;
  AREAD(1, 1);
  BAR; LGKM(0); SCHED0; QMFMA(1, 1, c); BAR;
  QMFMA(1, 0, b);                // final quadrant

  // ---- epilogue: C/D layout col=lane&15, row=(lane>>4)*4+j ----
  int crow = brow + wm * 128 + (lane >> 4) * 4;
  int ccol = bcol + wn * 64 + (lane & 15);
  #pragma unroll
  for (int mi = 0; mi < 8; ++mi)
    #pragma unroll
    for (int n = 0; n < 4; ++n)
      #pragma unroll
      for (int j = 0; j < 4; ++j)
        C[(size_t)(crow + mi * 16 + j) * MDIM + (ccol + n * 16)] = acc[mi][n][j];
}

extern "C" void kernel_launch(void* const* d_in, const int* in_sizes, int n_in,
                              void* d_out, int out_size, void* d_ws, size_t ws_size,
                              hipStream_t stream) {
  const float* x     = (const float*)d_in[0];
  const float* y     = (const float*)d_in[1];
  const float* freqs = (const float*)d_in[2];
  const float* lam   = (const float*)d_in[3];
  const float* var   = (const float*)d_in[4];
  float* out = (float*)d_out;
  float* ws  = (float*)d_ws;

  hipLaunchKernelGGL(scale_kernel, dim3(1), dim3(512), 0, stream, lam, var, ws);
  hipLaunchKernelGGL(phase_kernel, dim3((NDIM + MDIM) / PH_ROWS), dim3(256), 0, stream,
                     x, y, freqs, lam, ws);
  hipLaunchKernelGGL(gemm_kernel, dim3((NDIM / 256) * (MDIM / 256)), dim3(512), 0, stream,
                     out);
}